// Round 4
// baseline (2125.583 us; speedup 1.0000x reference)
//
#include <hip/hip_runtime.h>

// BlockSSM forward, MI355X. One persistent kernel: 256 blocks (1 per batch row),
// 512 threads (8 waves). Recurrence state x[128] lives in LDS (double-buffered),
// Wx/Wu/Wd/Wy rows live in VGPRs. fu/fd/y fused into the step loop.
// Raw s_barrier + manual lgkmcnt(0) per step (NOT __syncthreads -> would drain
// vmcnt and expose HBM latency of the u/d prefetch each step).
// u/d prefetch: 4-deep register pipeline (p0..p3), loads issued ~4 steps ahead.

#define NXC 128
#define NYC 32
#define NUC 32
#define NDC 16
#define NB  256
#define NT  2048

#define OFF_X  0
#define OFF_Y  (NT * NB * NXC)            // 67108864
#define OFF_FU (OFF_Y + NT * NB * NYC)    // 83886080
#define OFF_FD (OFF_FU + NT * NB * NXC)   // 150994944

__global__ __launch_bounds__(512) void ssm_fwd(
    const float* __restrict__ x0,
    const float* __restrict__ Uf,
    const float* __restrict__ Df,
    const float* __restrict__ Wx,
    const float* __restrict__ bxp,
    const float* __restrict__ Wu,
    const float* __restrict__ bup,
    const float* __restrict__ Wd,
    const float* __restrict__ bdp,
    const float* __restrict__ Wy,
    const float* __restrict__ byp,
    float* __restrict__ out)
{
    const int T = threadIdx.x;   // 0..511
    const int b = blockIdx.x;    // batch row
    const int i = T >> 2;        // x-output row 0..127
    const int q = T & 3;         // quarter of the 128-long dot
    const int j = T >> 4;        // y-output 0..31
    const int c = T & 15;        // y chunk 0..15

    __shared__ float xbuf[2][NXC];
    __shared__ float ubuf[2][NUC];
    __shared__ float dbuf[2][NDC];

    // ---- weights into registers (static indexing only) ----
    float wx[32];
#pragma unroll
    for (int kk = 0; kk < 8; ++kk) {
        float4 v = *reinterpret_cast<const float4*>(&Wx[i * NXC + q * 32 + kk * 4]);
        wx[kk*4+0] = v.x; wx[kk*4+1] = v.y; wx[kk*4+2] = v.z; wx[kk*4+3] = v.w;
    }
    float wu[8];
#pragma unroll
    for (int kk = 0; kk < 2; ++kk) {
        float4 v = *reinterpret_cast<const float4*>(&Wu[i * NUC + q * 8 + kk * 4]);
        wu[kk*4+0] = v.x; wu[kk*4+1] = v.y; wu[kk*4+2] = v.z; wu[kk*4+3] = v.w;
    }
    float wd[4];
    {
        float4 v = *reinterpret_cast<const float4*>(&Wd[i * NDC + q * 4]);
        wd[0] = v.x; wd[1] = v.y; wd[2] = v.z; wd[3] = v.w;
    }
    float wy[8];
#pragma unroll
    for (int kk = 0; kk < 2; ++kk) {
        float4 v = *reinterpret_cast<const float4*>(&Wy[j * NXC + c * 8 + kk * 4]);
        wy[kk*4+0] = v.x; wy[kk*4+1] = v.y; wy[kk*4+2] = v.z; wy[kk*4+3] = v.w;
    }
    const float bxv = bxp[i];
    const float buv = bup[i];
    const float bdv = bdp[i];
    const float byv = byp[j];

    // ---- prologue: stage x0 and ud(step 0); prefetch ud(1..4) into regs ----
    if (T < NXC) xbuf[0][T] = x0[b * NXC + T];

    const float* lbase = Uf;
    long lstride = 0;
    if (T < 32)      { lbase = Uf + (size_t)b * NUC + T;        lstride = NB * NUC; }
    else if (T < 48) { lbase = Df + (size_t)b * NDC + (T - 32); lstride = NB * NDC; }

    float p0 = 0.f, p1 = 0.f, p2 = 0.f, p3 = 0.f;
    const float* lp = lbase;
    if (T < 48) {
        float v0 = lbase[0];
        p0 = lbase[lstride];
        p1 = lbase[2 * lstride];
        p2 = lbase[3 * lstride];
        p3 = lbase[4 * lstride];
        lp = lbase + 5 * lstride;
        if (T < 32) ubuf[0][T] = v0; else dbuf[0][T - 32] = v0;
    }

    float* pX  = out + OFF_X  + (size_t)b * NXC;
    float* pFU = out + OFF_FU + (size_t)b * NXC;
    float* pFD = out + OFF_FD + (size_t)b * NXC;
    float* pY  = out + OFF_Y  + (size_t)b * NYC - (size_t)NB * NYC;  // row -1, never deref'd at t=0

    __builtin_amdgcn_sched_barrier(0);
    asm volatile("s_waitcnt lgkmcnt(0)" ::: "memory");
    __builtin_amdgcn_s_barrier();
    __builtin_amdgcn_sched_barrier(0);

    // One sub-step. CUR is a literal (0/1). PREG holds ud data for step t+1;
    // the load issued here targets step t+5 (4-deep pipeline).
    // Bank-conflict fix: rotate x-chunk iteration per quarter (kr) so the 4
    // quarters hit distinct bank groups; same for the y read (kr2).
#define SUBSTEP(t, CUR, PREG)                                                        \
    {                                                                                \
        const int nxt = (CUR) ^ 1;                                                   \
        float pnew = PREG;                                                           \
        if (T < 48 && ((t) + 5) < NT) { pnew = *lp; lp += lstride; }                 \
        float a0 = 0.f, a1 = 0.f, a2 = 0.f, a3 = 0.f;                                \
        _Pragma("unroll")                                                            \
        for (int kk = 0; kk < 8; ++kk) {                                             \
            const int kr = (kk + 2 * q) & 7;                                         \
            float4 xv = *reinterpret_cast<const float4*>(&xbuf[CUR][q * 32 + kr * 4]); \
            a0 = fmaf(wx[kr*4+0], xv.x, a0);                                         \
            a1 = fmaf(wx[kr*4+1], xv.y, a1);                                         \
            a2 = fmaf(wx[kr*4+2], xv.z, a2);                                         \
            a3 = fmaf(wx[kr*4+3], xv.w, a3);                                         \
        }                                                                            \
        float pAx = (a0 + a1) + (a2 + a3);                                           \
        float u0 = 0.f, u1 = 0.f;                                                    \
        _Pragma("unroll")                                                            \
        for (int kk = 0; kk < 2; ++kk) {                                             \
            float4 uv = *reinterpret_cast<const float4*>(&ubuf[CUR][q * 8 + kk * 4]); \
            u0 = fmaf(wu[kk*4+0], uv.x, u0);                                         \
            u1 = fmaf(wu[kk*4+1], uv.y, u1);                                         \
            u0 = fmaf(wu[kk*4+2], uv.z, u0);                                         \
            u1 = fmaf(wu[kk*4+3], uv.w, u1);                                         \
        }                                                                            \
        float pfu = u0 + u1;                                                         \
        float pfd;                                                                   \
        {                                                                            \
            float4 dv = *reinterpret_cast<const float4*>(&dbuf[CUR][q * 4]);         \
            pfd = fmaf(wd[0], dv.x, fmaf(wd[1], dv.y, fmaf(wd[2], dv.z, wd[3] * dv.w))); \
        }                                                                            \
        float y0 = 0.f, y1 = 0.f;                                                    \
        _Pragma("unroll")                                                            \
        for (int kk = 0; kk < 2; ++kk) {                                             \
            const int kr2 = (kk + (c >> 2)) & 1;                                     \
            float4 xv = *reinterpret_cast<const float4*>(&xbuf[CUR][c * 8 + kr2 * 4]); \
            y0 = fmaf(wy[kr2*4+0], xv.x, y0);                                        \
            y1 = fmaf(wy[kr2*4+1], xv.y, y1);                                        \
            y0 = fmaf(wy[kr2*4+2], xv.z, y0);                                        \
            y1 = fmaf(wy[kr2*4+3], xv.w, y1);                                        \
        }                                                                            \
        float py_ = y0 + y1;                                                         \
        pAx += __shfl_xor(pAx, 1);  pAx += __shfl_xor(pAx, 2);                       \
        pfu += __shfl_xor(pfu, 1);  pfu += __shfl_xor(pfu, 2);                       \
        pfd += __shfl_xor(pfd, 1);  pfd += __shfl_xor(pfd, 2);                       \
        py_ += __shfl_xor(py_, 1);  py_ += __shfl_xor(py_, 2);                       \
        py_ += __shfl_xor(py_, 4);  py_ += __shfl_xor(py_, 8);                       \
        const float fuv  = pfu + buv;                                                \
        const float fdv2 = pfd + bdv;                                                \
        const float xn   = 2.f * (pAx + bxv + fuv) + fdv2;                           \
        if ((T & 3) == 0) { xbuf[nxt][i] = xn; }                                     \
        if (T < 48) {                                                                \
            if (T < 32) ubuf[nxt][T] = PREG; else dbuf[nxt][T - 32] = PREG;          \
        }                                                                            \
        PREG = pnew;                                                                 \
        if ((T & 3) == 0) { pX[i] = xn; pFU[i] = fuv; pFD[i] = fdv2; }               \
        if ((t) > 0 && (T & 15) == 0) { pY[j] = py_ + byv; }                         \
        pX += NB * NXC; pFU += NB * NXC; pFD += NB * NXC; pY += NB * NYC;            \
        __builtin_amdgcn_sched_barrier(0);                                           \
        asm volatile("s_waitcnt lgkmcnt(0)" ::: "memory");                           \
        __builtin_amdgcn_s_barrier();                                                \
        __builtin_amdgcn_sched_barrier(0);                                           \
    }

#pragma unroll 1
    for (int m = 0; m < NT / 4; ++m) {
        const int t0 = m << 2;
        SUBSTEP(t0 + 0, 0, p0)
        SUBSTEP(t0 + 1, 1, p1)
        SUBSTEP(t0 + 2, 0, p2)
        SUBSTEP(t0 + 3, 1, p3)
    }
#undef SUBSTEP

    // Epilogue: Y[2047] from x_2048, which sits in xbuf[0] (2048 & 1 == 0).
    {
        float y0 = 0.f, y1 = 0.f;
#pragma unroll
        for (int kk = 0; kk < 2; ++kk) {
            float4 xv = *reinterpret_cast<const float4*>(&xbuf[0][c * 8 + kk * 4]);
            y0 = fmaf(wy[kk*4+0], xv.x, y0);
            y1 = fmaf(wy[kk*4+1], xv.y, y1);
            y0 = fmaf(wy[kk*4+2], xv.z, y0);
            y1 = fmaf(wy[kk*4+3], xv.w, y1);
        }
        float py_ = y0 + y1;
        py_ += __shfl_xor(py_, 1); py_ += __shfl_xor(py_, 2);
        py_ += __shfl_xor(py_, 4); py_ += __shfl_xor(py_, 8);
        if ((T & 15) == 0) pY[j] = py_ + byv;
    }
}

extern "C" void kernel_launch(void* const* d_in, const int* in_sizes, int n_in,
                              void* d_out, int out_size, void* d_ws, size_t ws_size,
                              hipStream_t stream) {
    const float* x0 = (const float*)d_in[0];
    // d_in[1] = Yf (unused by the reference computation)
    const float* Uf = (const float*)d_in[2];
    const float* Df = (const float*)d_in[3];
    const float* Wx = (const float*)d_in[4];
    const float* bx = (const float*)d_in[5];
    const float* Wu = (const float*)d_in[6];
    const float* bu = (const float*)d_in[7];
    const float* Wd = (const float*)d_in[8];
    const float* bd = (const float*)d_in[9];
    const float* Wy = (const float*)d_in[10];
    const float* by = (const float*)d_in[11];
    float* out = (float*)d_out;

    ssm_fwd<<<NB, 512, 0, stream>>>(x0, Uf, Df, Wx, bx, Wu, bu, Wd, bd, Wy, by, out);
}